// Round 2
// baseline (206.565 us; speedup 1.0000x reference)
//
#include <hip/hip_runtime.h>
#include <hip/hip_bf16.h>

#define N_NODES 8192
#define N_EDGES 524288
#define TOT_EDGES (N_EDGES + N_NODES)   /* 532480 */
#define IN_DIM 256
#define HID1 128
#define HID2 64
#define DC 128   /* combined [mu | lv] feature dim */

typedef __attribute__((ext_vector_type(8))) short bf16x8;
typedef __attribute__((ext_vector_type(4))) float f32x4;

// ---------------- CSR build ----------------

__global__ __launch_bounds__(256) void k_count(const int* __restrict__ ei, int* __restrict__ deg){
    int e = blockIdx.x*256 + threadIdx.x;
    if (e >= TOT_EDGES) return;
    int r = (e < N_EDGES) ? ei[e] : (e - N_EDGES);
    atomicAdd(&deg[r], 1);
}

__global__ __launch_bounds__(1024) void k_scan(const int* __restrict__ deg, int* __restrict__ rowPtr){
    __shared__ int lds[1024];
    int tid = threadIdx.x;
    int base = tid*8;
    int v[8]; int s = 0;
    #pragma unroll
    for (int k=0;k<8;k++){ v[k] = s; s += deg[base+k]; }
    lds[tid] = s;
    __syncthreads();
    for (int off=1; off<1024; off<<=1){
        int t = (tid >= off) ? lds[tid-off] : 0;
        __syncthreads();
        lds[tid] += t;
        __syncthreads();
    }
    int excl = (tid==0) ? 0 : lds[tid-1];
    #pragma unroll
    for (int k=0;k<8;k++) rowPtr[base+k] = excl + v[k];
    if (tid == 1023) rowPtr[N_NODES] = lds[1023];   // index 8192 — buffer must hold 8193 ints
}

__global__ __launch_bounds__(256) void k_dinv(const int* __restrict__ deg, float* __restrict__ dinv){
    int i = blockIdx.x*256 + threadIdx.x;
    if (i < N_NODES){
        int d = deg[i];
        dinv[i] = (d > 0) ? rsqrtf((float)d) : 0.f;
    }
}

__global__ __launch_bounds__(256) void k_fill(const int* __restrict__ ei, const int* __restrict__ rowPtr,
                                              int* __restrict__ fill, int* __restrict__ csr_col){
    int e = blockIdx.x*256 + threadIdx.x;
    if (e >= TOT_EDGES) return;
    int r, c;
    if (e < N_EDGES){ r = ei[e]; c = ei[N_EDGES + e]; }
    else            { r = e - N_EDGES; c = r; }
    int pos = rowPtr[r] + atomicAdd(&fill[r], 1);
    csr_col[pos] = c;
}

// ---------------- weight folding: Wc = [W1@Wmu_t + W2@Wmu_b | W1@Wlv_t + W2@Wlv_b] ----------------

__global__ __launch_bounds__(128) void k_wcomb(const float* __restrict__ W1, const float* __restrict__ W2,
                                               const float* __restrict__ Wmu, const float* __restrict__ Wlv,
                                               const float* __restrict__ b1, const float* __restrict__ b2,
                                               float* __restrict__ Wc, float* __restrict__ cvec){
    int r = blockIdx.x;        // 0..255 (input dim)
    int j = threadIdx.x;       // 0..127 — wave 0: mu cols, wave 1: lv cols (wave-uniform select)
    const float* Wsel = (j < 64) ? Wmu : Wlv;
    int jj = j & 63;
    float acc = 0.f;
    for (int k=0;k<HID1;k++){
        acc += W1[r*HID1+k] * Wsel[k*HID2+jj] + W2[r*HID1+k] * Wsel[(HID1+k)*HID2+jj];
    }
    Wc[r*DC + j] = acc;
    if (r == 0){
        float c = 0.f;
        for (int k=0;k<HID1;k++){
            c += b1[k]*Wsel[k*HID2+jj] + b2[k]*Wsel[(HID1+k)*HID2+jj];
        }
        cvec[j] = c;
    }
}

// ---------------- U = x @ Wc  (8192x256 @ 256x128) ----------------

__global__ __launch_bounds__(256) void k_gemm_u(const float* __restrict__ X, const float* __restrict__ Wc,
                                                float* __restrict__ U){
    int j  = threadIdx.x & (DC-1);
    int rg = threadIdx.x >> 7;          // 0..1, wave-pair-uniform
    int i0 = blockIdx.x*8 + rg*4;
    float acc[4] = {0.f,0.f,0.f,0.f};
    for (int k=0;k<IN_DIM;k++){
        float w = Wc[k*DC + j];
        #pragma unroll
        for (int rr=0;rr<4;rr++) acc[rr] += X[(size_t)(i0+rr)*IN_DIM + k] * w;
    }
    #pragma unroll
    for (int rr=0;rr<4;rr++) U[(size_t)(i0+rr)*DC + j] = acc[rr];
}

// ---------------- SpMM: OUT = Â * IN  (128-dim features, gather-style via CSR) ----------------

__global__ __launch_bounds__(128) void k_spmm(const float* __restrict__ IN, const int* __restrict__ rowPtr,
                                              const int* __restrict__ csr_col, const float* __restrict__ dinv,
                                              float* __restrict__ OUT){
    int i = blockIdx.x;
    int tid = threadIdx.x;
    int beg = rowPtr[i], end = rowPtr[i+1];
    __shared__ int   s_col[128];
    __shared__ float s_w[128];
    float acc = 0.f;
    for (int base = beg; base < end; base += 128){
        int nch = min(128, end - base);
        if (tid < nch){
            int c = csr_col[base + tid];
            s_col[tid] = c;
            s_w[tid]   = dinv[c];
        }
        __syncthreads();
        for (int e=0; e<nch; e++){
            acc += s_w[e] * IN[(size_t)s_col[e]*DC + tid];
        }
        __syncthreads();
    }
    OUT[(size_t)i*DC + tid] = dinv[i]*acc;
}

// Second propagation, fused with bias rank-1 term + output writes (mu f32, lv f32, mu bf16)

__global__ __launch_bounds__(128) void k_spmm_out(const float* __restrict__ T, const int* __restrict__ rowPtr,
                                                  const int* __restrict__ csr_col, const float* __restrict__ dinv,
                                                  const float* __restrict__ cvec,
                                                  const float* __restrict__ bmu, const float* __restrict__ blv,
                                                  float* __restrict__ outMu, float* __restrict__ outLv,
                                                  __hip_bfloat16* __restrict__ muBf){
    int i = blockIdx.x;
    int tid = threadIdx.x;
    int beg = rowPtr[i], end = rowPtr[i+1];
    __shared__ int   s_col[128];
    __shared__ float s_w[128];
    float acc = 0.f, wsum = 0.f;
    for (int base = beg; base < end; base += 128){
        int nch = min(128, end - base);
        if (tid < nch){
            int c = csr_col[base + tid];
            s_col[tid] = c;
            s_w[tid]   = dinv[c];
        }
        __syncthreads();
        for (int e=0; e<nch; e++){
            float w = s_w[e];
            wsum += w;
            acc  += w * T[(size_t)s_col[e]*DC + tid];
        }
        __syncthreads();
    }
    float di  = dinv[i];
    float sv  = di * wsum;                       // s = (Â·1)_i
    float val = di*acc + sv*cvec[tid] + ((tid < 64) ? bmu[tid] : blv[tid-64]);
    if (tid < 64){
        outMu[(size_t)i*HID2 + tid] = val;
        muBf[(size_t)i*HID2 + tid]  = __float2bfloat16(val);
    } else {
        outLv[(size_t)i*HID2 + (tid-64)] = val;
    }
}

// ---------------- adj = sigmoid(mu @ mu^T)  via bf16 MFMA 16x16x32 ----------------
// Block: 256 thr = 4 waves (2x2 of 64x64). Wave: 4x4 tiles of 16x16, K=64 (2 MFMA k-chunks).

__global__ __launch_bounds__(256) void k_adj(const unsigned short* __restrict__ mu, float* __restrict__ adj){
    int l  = threadIdx.x & 63;
    int w  = threadIdx.x >> 6;
    int wr = w >> 1, wc = w & 1;
    int Ibase = blockIdx.y*128 + wr*64;
    int Jbase = blockIdx.x*128 + wc*64;
    int lr = l & 15;        // row within 16-tile (A) / col (B,C)
    int kg = l >> 4;        // k-group 0..3

    bf16x8 afr[4][2], bfr[4][2];
    #pragma unroll
    for (int mt=0; mt<4; mt++){
        const unsigned short* p = mu + (size_t)(Ibase + mt*16 + lr)*HID2 + kg*8;
        afr[mt][0] = *(const bf16x8*)(p);
        afr[mt][1] = *(const bf16x8*)(p + 32);
    }
    #pragma unroll
    for (int nt=0; nt<4; nt++){
        const unsigned short* p = mu + (size_t)(Jbase + nt*16 + lr)*HID2 + kg*8;
        bfr[nt][0] = *(const bf16x8*)(p);
        bfr[nt][1] = *(const bf16x8*)(p + 32);
    }

    f32x4 acc[4][4];
    #pragma unroll
    for (int mt=0; mt<4; mt++)
        #pragma unroll
        for (int nt=0; nt<4; nt++)
            acc[mt][nt] = (f32x4){0.f,0.f,0.f,0.f};

    #pragma unroll
    for (int kc=0; kc<2; kc++)
        #pragma unroll
        for (int mt=0; mt<4; mt++)
            #pragma unroll
            for (int nt=0; nt<4; nt++)
                acc[mt][nt] = __builtin_amdgcn_mfma_f32_16x16x32_bf16(afr[mt][kc], bfr[nt][kc], acc[mt][nt], 0, 0, 0);

    // C/D layout: col = lane&15, row = (lane>>4)*4 + reg   [HW-verified]
    #pragma unroll
    for (int mt=0; mt<4; mt++){
        #pragma unroll
        for (int r=0; r<4; r++){
            int grow = Ibase + mt*16 + kg*4 + r;
            float* dst = adj + (size_t)grow*N_NODES + Jbase;
            #pragma unroll
            for (int nt=0; nt<4; nt++){
                float v = acc[mt][nt][r];
                dst[nt*16 + lr] = 1.f/(1.f + __expf(-v));
            }
        }
    }
}

// ---------------- launch ----------------

extern "C" void kernel_launch(void* const* d_in, const int* in_sizes, int n_in,
                              void* d_out, int out_size, void* d_ws, size_t ws_size,
                              hipStream_t stream){
    const float* x   = (const float*)d_in[0];
    const int*   ei  = (const int*)  d_in[1];
    const float* W1  = (const float*)d_in[2];
    const float* b1  = (const float*)d_in[3];
    const float* W2  = (const float*)d_in[4];
    const float* b2  = (const float*)d_in[5];
    const float* Wmu = (const float*)d_in[6];
    const float* bmu = (const float*)d_in[7];
    const float* Wlv = (const float*)d_in[8];
    const float* blv = (const float*)d_in[9];

    // workspace layout (small buffers only; big scratch lives in d_out's adj region)
    char* ws = (char*)d_ws;
    int*   deg    = (int*)  (ws + 0);        // 32768 B  (8192 ints)
    int*   rowPtr = (int*)  (ws + 32768);    // 36864 B  (8193 ints + pad)  <-- fixed: was 32 KB, overflowed
    int*   fill   = (int*)  (ws + 69632);    // 32768 B
    float* dinv   = (float*)(ws + 102400);   // 32768 B
    int*   csrcol = (int*)  (ws + 135168);   // 532480*4 = 2,129,920 B -> ends 2,265,088
    float* Wc     = (float*)(ws + 2265088);  // 131072 B -> ends 2,396,160
    float* cvec   = (float*)(ws + 2396160);  // 512 B
    __hip_bfloat16* muBf = (__hip_bfloat16*)(ws + 2396672); // 1 MB -> ends ~3.4 MB

    float* adj   = (float*)d_out;
    float* outMu = adj + (size_t)N_NODES*N_NODES;
    float* outLv = outMu + (size_t)N_NODES*HID2;

    // U and T are dead before k_adj runs -> stage them inside the adj region (268 MB)
    float* U = adj;                           // 4 MB
    float* T = adj + (size_t)4*1024*1024;     // next 4 MB (disjoint)

    hipMemsetAsync(d_ws, 0, 135168, stream);  // zero deg + rowPtr + fill (+dinv, rewritten anyway)

    k_count<<<TOT_EDGES/256, 256, 0, stream>>>(ei, deg);
    k_scan <<<1, 1024, 0, stream>>>(deg, rowPtr);
    k_dinv <<<N_NODES/256, 256, 0, stream>>>(deg, dinv);
    k_fill <<<TOT_EDGES/256, 256, 0, stream>>>(ei, rowPtr, fill, csrcol);

    k_wcomb<<<IN_DIM, 128, 0, stream>>>(W1, W2, Wmu, Wlv, b1, b2, Wc, cvec);
    k_gemm_u<<<N_NODES/8, 256, 0, stream>>>(x, Wc, U);

    k_spmm    <<<N_NODES, 128, 0, stream>>>(U, rowPtr, csrcol, dinv, T);
    k_spmm_out<<<N_NODES, 128, 0, stream>>>(T, rowPtr, csrcol, dinv, cvec, bmu, blv,
                                            outMu, outLv, muBf);

    k_adj<<<dim3(N_NODES/128, N_NODES/128), 256, 0, stream>>>((const unsigned short*)muBf, adj);
}

// Round 3
// 192.201 us; speedup vs baseline: 1.0747x; 1.0747x over previous
//
#include <hip/hip_runtime.h>
#include <hip/hip_bf16.h>

#define N_NODES 8192
#define N_EDGES 524288
#define TOT_EDGES (N_EDGES + N_NODES)   /* 532480 */
#define IN_DIM 256
#define HID1 128
#define HID2 64
#define DC 128   /* combined [mu | lv] feature dim */

typedef __attribute__((ext_vector_type(8))) short bf16x8;
typedef __attribute__((ext_vector_type(4))) float f32x4;
typedef __attribute__((ext_vector_type(4))) unsigned short u16x4;

// ---------------- CSR build ----------------

__global__ __launch_bounds__(256) void k_count(const int* __restrict__ ei, int* __restrict__ deg){
    int e = blockIdx.x*256 + threadIdx.x;
    if (e >= TOT_EDGES) return;
    int r = (e < N_EDGES) ? ei[e] : (e - N_EDGES);
    atomicAdd(&deg[r], 1);
}

// prefix-scan of degrees + fused dinv = rsqrt(deg)
__global__ __launch_bounds__(1024) void k_scan(const int* __restrict__ deg, int* __restrict__ rowPtr,
                                               float* __restrict__ dinv){
    __shared__ int lds[1024];
    int tid = threadIdx.x;
    int base = tid*8;
    int d[8], v[8]; int s = 0;
    #pragma unroll
    for (int k=0;k<8;k++){ d[k] = deg[base+k]; v[k] = s; s += d[k]; }
    lds[tid] = s;
    __syncthreads();
    for (int off=1; off<1024; off<<=1){
        int t = (tid >= off) ? lds[tid-off] : 0;
        __syncthreads();
        lds[tid] += t;
        __syncthreads();
    }
    int excl = (tid==0) ? 0 : lds[tid-1];
    #pragma unroll
    for (int k=0;k<8;k++){
        rowPtr[base+k] = excl + v[k];
        dinv[base+k]   = (d[k] > 0) ? rsqrtf((float)d[k]) : 0.f;
    }
    if (tid == 1023) rowPtr[N_NODES] = lds[1023];   // index 8192 (buffer holds 8193)
}

__global__ __launch_bounds__(256) void k_fill(const int* __restrict__ ei, const int* __restrict__ rowPtr,
                                              int* __restrict__ fill, int* __restrict__ csr_col){
    int e = blockIdx.x*256 + threadIdx.x;
    if (e >= TOT_EDGES) return;
    int r, c;
    if (e < N_EDGES){ r = ei[e]; c = ei[N_EDGES + e]; }
    else            { r = e - N_EDGES; c = r; }
    int pos = rowPtr[r] + atomicAdd(&fill[r], 1);
    csr_col[pos] = c;
}

// ---------------- weight folding: WcT (bf16, [j][k] transposed) + cvec ----------------

__global__ __launch_bounds__(128) void k_wcomb(const float* __restrict__ W1, const float* __restrict__ W2,
                                               const float* __restrict__ Wmu, const float* __restrict__ Wlv,
                                               const float* __restrict__ b1, const float* __restrict__ b2,
                                               unsigned short* __restrict__ WcT, float* __restrict__ cvec){
    int r = blockIdx.x;        // 0..255 (input dim = k)
    int j = threadIdx.x;       // 0..127 — wave 0: mu cols, wave 1: lv cols (wave-uniform select)
    const float* Wsel = (j < 64) ? Wmu : Wlv;
    int jj = j & 63;
    float acc = 0.f;
    for (int k=0;k<HID1;k++){
        acc += W1[r*HID1+k] * Wsel[k*HID2+jj] + W2[r*HID1+k] * Wsel[(HID1+k)*HID2+jj];
    }
    __hip_bfloat16 h = __float2bfloat16(acc);
    WcT[(size_t)j*IN_DIM + r] = *(unsigned short*)&h;     // transposed, bf16
    if (r == 0){
        float c = 0.f;
        for (int k=0;k<HID1;k++){
            c += b1[k]*Wsel[k*HID2+jj] + b2[k]*Wsel[(HID1+k)*HID2+jj];
        }
        cvec[j] = c;
    }
}

// ---------------- x -> bf16 ----------------

__global__ __launch_bounds__(256) void k_xcvt(const float* __restrict__ x, unsigned short* __restrict__ xbf){
    int g = (blockIdx.x*256 + threadIdx.x)*4;
    f32x4 v = *(const f32x4*)(x + g);
    u16x4 o;
    #pragma unroll
    for (int j=0;j<4;j++){ __hip_bfloat16 h = __float2bfloat16(v[j]); o[j] = *(unsigned short*)&h; }
    *(u16x4*)(xbf + g) = o;
}

// ---------------- U = x @ Wc  via bf16 MFMA (out f32) ----------------
// block = 256 thr (4 waves). Block tile 32 rows x 128 cols; wave tile 32x32.

__global__ __launch_bounds__(256) void k_gemm_u(const unsigned short* __restrict__ xbf,
                                                const unsigned short* __restrict__ WcT,
                                                float* __restrict__ U){
    int l  = threadIdx.x & 63;
    int w  = threadIdx.x >> 6;          // wave id 0..3 -> col group
    int Ibase = blockIdx.x*32;
    int Jbase = w*32;
    int lr = l & 15;
    int kg = l >> 4;

    f32x4 acc[2][2];
    #pragma unroll
    for (int mt=0;mt<2;mt++)
        #pragma unroll
        for (int nt=0;nt<2;nt++) acc[mt][nt] = (f32x4){0.f,0.f,0.f,0.f};

    #pragma unroll
    for (int kc=0; kc<IN_DIM/32; kc++){
        bf16x8 a[2], b[2];
        #pragma unroll
        for (int mt=0;mt<2;mt++)
            a[mt] = *(const bf16x8*)(xbf + (size_t)(Ibase+mt*16+lr)*IN_DIM + kc*32 + kg*8);
        #pragma unroll
        for (int nt=0;nt<2;nt++)
            b[nt] = *(const bf16x8*)(WcT + (size_t)(Jbase+nt*16+lr)*IN_DIM + kc*32 + kg*8);
        #pragma unroll
        for (int mt=0;mt<2;mt++)
            #pragma unroll
            for (int nt=0;nt<2;nt++)
                acc[mt][nt] = __builtin_amdgcn_mfma_f32_16x16x32_bf16(a[mt], b[nt], acc[mt][nt], 0, 0, 0);
    }
    // C/D: col = lane&15, row = (lane>>4)*4 + reg
    #pragma unroll
    for (int mt=0;mt<2;mt++)
        #pragma unroll
        for (int r=0;r<4;r++){
            int grow = Ibase + mt*16 + kg*4 + r;
            #pragma unroll
            for (int nt=0;nt<2;nt++)
                U[(size_t)grow*DC + Jbase + nt*16 + lr] = acc[mt][nt][r];
        }
}

// ---------------- SpMM: OUT = Â * IN  (f32x4 gathers, 4 edges in parallel) ----------------

__global__ __launch_bounds__(128) void k_spmm(const float* __restrict__ IN, const int* __restrict__ rowPtr,
                                              const int* __restrict__ csr_col, const float* __restrict__ dinv,
                                              float* __restrict__ OUT){
    int i = blockIdx.x;
    int tid = threadIdx.x;
    int lane = tid & 31, eg = tid >> 5;
    int beg = rowPtr[i], end = rowPtr[i+1];
    __shared__ int   s_col[128];
    __shared__ float s_w[128];
    __shared__ f32x4 s_red[96];
    f32x4 acc = (f32x4){0.f,0.f,0.f,0.f};
    for (int base = beg; base < end; base += 128){
        int nch  = min(128, end - base);
        int nchp = (nch + 3) & ~3;
        if (tid < nchp){
            if (tid < nch){ int c = csr_col[base + tid]; s_col[tid] = c; s_w[tid] = dinv[c]; }
            else          { s_col[tid] = 0; s_w[tid] = 0.f; }
        }
        __syncthreads();
        #pragma unroll 2
        for (int e = eg; e < nchp; e += 4){
            int c = s_col[e]; float wgt = s_w[e];
            f32x4 v = *(const f32x4*)(IN + (size_t)c*DC + lane*4);
            #pragma unroll
            for (int j=0;j<4;j++) acc[j] += wgt * v[j];
        }
        __syncthreads();
    }
    if (tid >= 32) s_red[tid-32] = acc;
    __syncthreads();
    if (tid < 32){
        f32x4 r = acc;
        #pragma unroll
        for (int g=0; g<3; g++){
            f32x4 t = s_red[tid + g*32];
            #pragma unroll
            for (int j=0;j<4;j++) r[j] += t[j];
        }
        float di = dinv[i];
        #pragma unroll
        for (int j=0;j<4;j++) r[j] *= di;
        *(f32x4*)(OUT + (size_t)i*DC + tid*4) = r;
    }
}

// Second propagation + rank-1 bias term + outputs (mu f32, lv f32, mu bf16)

__global__ __launch_bounds__(128) void k_spmm_out(const float* __restrict__ T, const int* __restrict__ rowPtr,
                                                  const int* __restrict__ csr_col, const float* __restrict__ dinv,
                                                  const float* __restrict__ cvec,
                                                  const float* __restrict__ bmu, const float* __restrict__ blv,
                                                  float* __restrict__ outMu, float* __restrict__ outLv,
                                                  unsigned short* __restrict__ muBf){
    int i = blockIdx.x;
    int tid = threadIdx.x;
    int lane = tid & 31, eg = tid >> 5;
    int beg = rowPtr[i], end = rowPtr[i+1];
    __shared__ int   s_col[128];
    __shared__ float s_w[128];
    __shared__ f32x4 s_red[96];
    __shared__ float s_wred[4];
    f32x4 acc = (f32x4){0.f,0.f,0.f,0.f};
    float wsum = 0.f;
    for (int base = beg; base < end; base += 128){
        int nch  = min(128, end - base);
        int nchp = (nch + 3) & ~3;
        if (tid < nchp){
            if (tid < nch){ int c = csr_col[base + tid]; s_col[tid] = c; s_w[tid] = dinv[c]; }
            else          { s_col[tid] = 0; s_w[tid] = 0.f; }
        }
        __syncthreads();
        #pragma unroll 2
        for (int e = eg; e < nchp; e += 4){
            int c = s_col[e]; float wgt = s_w[e];
            wsum += wgt;
            f32x4 v = *(const f32x4*)(T + (size_t)c*DC + lane*4);
            #pragma unroll
            for (int j=0;j<4;j++) acc[j] += wgt * v[j];
        }
        __syncthreads();
    }
    if (tid >= 32) s_red[tid-32] = acc;
    if (lane == 0) s_wred[eg] = wsum;
    __syncthreads();
    if (tid < 32){
        f32x4 r = acc;
        #pragma unroll
        for (int g=0; g<3; g++){
            f32x4 t = s_red[tid + g*32];
            #pragma unroll
            for (int j=0;j<4;j++) r[j] += t[j];
        }
        float di = dinv[i];
        float sv = di * (s_wred[0] + s_wred[1] + s_wred[2] + s_wred[3]);   // (Â·1)_i
        f32x4 cv = *(const f32x4*)(cvec + tid*4);
        f32x4 val;
        if (tid < 16){
            f32x4 bb = *(const f32x4*)(bmu + tid*4);
            #pragma unroll
            for (int j=0;j<4;j++) val[j] = di*r[j] + sv*cv[j] + bb[j];
            *(f32x4*)(outMu + (size_t)i*HID2 + tid*4) = val;
            u16x4 o;
            #pragma unroll
            for (int j=0;j<4;j++){ __hip_bfloat16 h = __float2bfloat16(val[j]); o[j] = *(unsigned short*)&h; }
            *(u16x4*)(muBf + (size_t)i*HID2 + tid*4) = o;
        } else {
            f32x4 bb = *(const f32x4*)(blv + (tid-16)*4);
            #pragma unroll
            for (int j=0;j<4;j++) val[j] = di*r[j] + sv*cv[j] + bb[j];
            *(f32x4*)(outLv + (size_t)i*HID2 + (tid-16)*4) = val;
        }
    }
}

// ---------------- adj = sigmoid(mu @ mu^T)  via bf16 MFMA 16x16x32 ----------------

__global__ __launch_bounds__(256) void k_adj(const unsigned short* __restrict__ mu, float* __restrict__ adj){
    int l  = threadIdx.x & 63;
    int w  = threadIdx.x >> 6;
    int wr = w >> 1, wc = w & 1;
    int Ibase = blockIdx.y*128 + wr*64;
    int Jbase = blockIdx.x*128 + wc*64;
    int lr = l & 15;
    int kg = l >> 4;

    bf16x8 afr[4][2], bfr[4][2];
    #pragma unroll
    for (int mt=0; mt<4; mt++){
        const unsigned short* p = mu + (size_t)(Ibase + mt*16 + lr)*HID2 + kg*8;
        afr[mt][0] = *(const bf16x8*)(p);
        afr[mt][1] = *(const bf16x8*)(p + 32);
    }
    #pragma unroll
    for (int nt=0; nt<4; nt++){
        const unsigned short* p = mu + (size_t)(Jbase + nt*16 + lr)*HID2 + kg*8;
        bfr[nt][0] = *(const bf16x8*)(p);
        bfr[nt][1] = *(const bf16x8*)(p + 32);
    }

    f32x4 acc[4][4];
    #pragma unroll
    for (int mt=0; mt<4; mt++)
        #pragma unroll
        for (int nt=0; nt<4; nt++)
            acc[mt][nt] = (f32x4){0.f,0.f,0.f,0.f};

    #pragma unroll
    for (int kc=0; kc<2; kc++)
        #pragma unroll
        for (int mt=0; mt<4; mt++)
            #pragma unroll
            for (int nt=0; nt<4; nt++)
                acc[mt][nt] = __builtin_amdgcn_mfma_f32_16x16x32_bf16(afr[mt][kc], bfr[nt][kc], acc[mt][nt], 0, 0, 0);

    #pragma unroll
    for (int mt=0; mt<4; mt++){
        #pragma unroll
        for (int r=0; r<4; r++){
            int grow = Ibase + mt*16 + kg*4 + r;
            float* dst = adj + (size_t)grow*N_NODES + Jbase;
            #pragma unroll
            for (int nt=0; nt<4; nt++){
                float v = acc[mt][nt][r];
                __builtin_nontemporal_store(1.f/(1.f + __expf(-v)), dst + nt*16 + lr);
            }
        }
    }
}

// ---------------- launch ----------------

extern "C" void kernel_launch(void* const* d_in, const int* in_sizes, int n_in,
                              void* d_out, int out_size, void* d_ws, size_t ws_size,
                              hipStream_t stream){
    const float* x   = (const float*)d_in[0];
    const int*   ei  = (const int*)  d_in[1];
    const float* W1  = (const float*)d_in[2];
    const float* b1  = (const float*)d_in[3];
    const float* W2  = (const float*)d_in[4];
    const float* b2  = (const float*)d_in[5];
    const float* Wmu = (const float*)d_in[6];
    const float* bmu = (const float*)d_in[7];
    const float* Wlv = (const float*)d_in[8];
    const float* blv = (const float*)d_in[9];

    char* ws = (char*)d_ws;
    int*   deg    = (int*)  (ws + 0);        // 32768 B
    int*   rowPtr = (int*)  (ws + 32768);    // 8193 ints (+pad)
    int*   fill   = (int*)  (ws + 69632);    // 32768 B
    float* dinv   = (float*)(ws + 102400);   // 32768 B
    int*   csrcol = (int*)  (ws + 135168);   // 2,129,920 B -> 2,265,088
    unsigned short* WcT = (unsigned short*)(ws + 2265088); // 128x256 bf16 = 65536 -> 2,330,624
    float* cvec   = (float*)(ws + 2330624);  // 512 B -> 2,331,136
    unsigned short* muBf = (unsigned short*)(ws + 2331136); // 1 MB -> 3,379,712
    unsigned short* xbf  = (unsigned short*)(ws + 3379712); // 4 MB -> 7,574,016

    float* adj   = (float*)d_out;
    float* outMu = adj + (size_t)N_NODES*N_NODES;
    float* outLv = outMu + (size_t)N_NODES*HID2;

    // U, T are dead before k_adj -> stage in the adj region (268 MB)
    float* U = adj;                           // 4 MB
    float* T = adj + (size_t)4*1024*1024;     // next 4 MB

    hipMemsetAsync(d_ws, 0, 102400, stream);  // zero deg + rowPtr + fill

    k_count<<<TOT_EDGES/256, 256, 0, stream>>>(ei, deg);
    k_scan <<<1, 1024, 0, stream>>>(deg, rowPtr, dinv);
    k_fill <<<TOT_EDGES/256, 256, 0, stream>>>(ei, rowPtr, fill, csrcol);

    k_wcomb<<<IN_DIM, 128, 0, stream>>>(W1, W2, Wmu, Wlv, b1, b2, WcT, cvec);
    k_xcvt <<<(N_NODES*IN_DIM)/1024, 256, 0, stream>>>(x, xbf);
    k_gemm_u<<<N_NODES/32, 256, 0, stream>>>(xbf, WcT, U);

    k_spmm    <<<N_NODES, 128, 0, stream>>>(U, rowPtr, csrcol, dinv, T);
    k_spmm_out<<<N_NODES, 128, 0, stream>>>(T, rowPtr, csrcol, dinv, cvec, bmu, blv,
                                            outMu, outLv, muBf);

    k_adj<<<dim3(N_NODES/128, N_NODES/128), 256, 0, stream>>>(muBf, adj);
}